// Round 1
// baseline (160.107 us; speedup 1.0000x reference)
//
#include <hip/hip_runtime.h>
#include <hip/hip_bf16.h>
#include <stdint.h>

#define N_ROWS 4096
#define D_DIM  1024
#define KBYTES 2048   // D_DIM * sizeof(bf16)
#define T_TEMP 0.15f

typedef float  f32x4  __attribute__((ext_vector_type(4)));
typedef __bf16 bf16x8 __attribute__((ext_vector_type(8)));

__device__ __forceinline__ unsigned short f2bf(float f) {
  unsigned u = __float_as_uint(f);
  u += 0x7FFF + ((u >> 16) & 1);   // RNE
  return (unsigned short)(u >> 16);
}

__device__ __forceinline__ float bsum(float v, float* s, int tid) {
#pragma unroll
  for (int m = 32; m >= 1; m >>= 1) v += __shfl_xor(v, m, 64);
  if ((tid & 63) == 0) s[tid >> 6] = v;
  __syncthreads();
  v = s[0] + s[1] + s[2] + s[3];
  __syncthreads();
  return v;
}

__device__ __forceinline__ float bmax(float v, float* s, int tid) {
#pragma unroll
  for (int m = 32; m >= 1; m >>= 1) v = fmaxf(v, __shfl_xor(v, m, 64));
  if ((tid & 63) == 0) s[tid >> 6] = v;
  __syncthreads();
  v = fmaxf(fmaxf(s[0], s[1]), fmaxf(s[2], s[3]));
  __syncthreads();
  return v;
}

// One block per row: norms, x.y dot (-> log pos), softmax-JS terms, bf16 casts.
__global__ __launch_bounds__(256) void prep_kernel(
    const float* __restrict__ x, const float* __restrict__ y,
    unsigned short* __restrict__ Bb, float* __restrict__ inv_n,
    float* __restrict__ logpos, float* __restrict__ js_acc) {
  __shared__ float s[4];
  const int row = blockIdx.x, tid = threadIdx.x;
  const float4 xv = ((const float4*)(x + (size_t)row * D_DIM))[tid];
  const float4 yv = ((const float4*)(y + (size_t)row * D_DIM))[tid];

  float sx2 = xv.x*xv.x + xv.y*xv.y + xv.z*xv.z + xv.w*xv.w;
  float sy2 = yv.x*yv.x + yv.y*yv.y + yv.z*yv.z + yv.w*yv.w;
  float sxy = xv.x*yv.x + xv.y*yv.y + xv.z*yv.z + xv.w*yv.w;
  float mx  = fmaxf(fmaxf(xv.x, xv.y), fmaxf(xv.z, xv.w));
  float my  = fmaxf(fmaxf(yv.x, yv.y), fmaxf(yv.z, yv.w));

  sx2 = bsum(sx2, s, tid);
  sy2 = bsum(sy2, s, tid);
  sxy = bsum(sxy, s, tid);
  mx  = bmax(mx, s, tid);
  my  = bmax(my, s, tid);

  const float ex0 = expf(xv.x - mx), ex1 = expf(xv.y - mx),
              ex2 = expf(xv.z - mx), ex3 = expf(xv.w - mx);
  const float ey0 = expf(yv.x - my), ey1 = expf(yv.y - my),
              ey2 = expf(yv.z - my), ey3 = expf(yv.w - my);
  const float sex = bsum(ex0 + ex1 + ex2 + ex3, s, tid);
  const float sey = bsum(ey0 + ey1 + ey2 + ey3, s, tid);
  const float lsex = logf(sex), lsey = logf(sey);

  float term = 0.f;
  {
    float a, b, m2;
    a = ex0 / sex; b = ey0 / sey; m2 = 0.5f * (a + b);
    term += a * ((xv.x - mx - lsex) - logf(m2)) + b * ((yv.x - my - lsey) - logf(m2));
    a = ex1 / sex; b = ey1 / sey; m2 = 0.5f * (a + b);
    term += a * ((xv.y - mx - lsex) - logf(m2)) + b * ((yv.y - my - lsey) - logf(m2));
    a = ex2 / sex; b = ey2 / sey; m2 = 0.5f * (a + b);
    term += a * ((xv.z - mx - lsex) - logf(m2)) + b * ((yv.z - my - lsey) - logf(m2));
    a = ex3 / sex; b = ey3 / sey; m2 = 0.5f * (a + b);
    term += a * ((xv.w - mx - lsex) - logf(m2)) + b * ((yv.w - my - lsey) - logf(m2));
  }
  term = bsum(term, s, tid);

  if (tid == 0) {
    const float nx = sqrtf(sx2), ny = sqrtf(sy2);
    inv_n[row] = 1.0f / nx;
    inv_n[N_ROWS + row] = 1.0f / ny;
    logpos[row] = sxy / fmaxf(nx * ny, 1e-8f) / T_TEMP;  // natural-log of pos
    atomicAdd(js_acc, term);
  }

  ushort4 px = make_ushort4(f2bf(xv.x), f2bf(xv.y), f2bf(xv.z), f2bf(xv.w));
  ushort4 py = make_ushort4(f2bf(yv.x), f2bf(yv.y), f2bf(yv.z), f2bf(yv.w));
  *(ushort4*)(Bb + (size_t)row * D_DIM + tid * 4) = px;
  *(ushort4*)(Bb + (size_t)(N_ROWS + row) * D_DIM + tid * 4) = py;
}

// Fused GEMM: A = rows [0,4096) of Bb (=x), B = all 8192 rows (=[x;y]), BT layout.
// Epilogue: exp2(dot * inv_n_i * inv_n_j * log2e/T), mask j==i and j==i+4096,
// per-row sum -> atomicAdd into rowsum.
__global__ __launch_bounds__(256) void gemm_fused(
    const unsigned short* __restrict__ Bb, const float* __restrict__ inv_n,
    float* __restrict__ rowsum) {
  __shared__ __align__(16) unsigned short As[128 * 32];
  __shared__ __align__(16) unsigned short Bs[128 * 32];
  const int tid = threadIdx.x;
  const int wid = tid >> 6, lane = tid & 63;
  const int lo = lane & 15, hi = lane >> 4;
  const int grow0 = blockIdx.x * 128;
  const int gcol0 = blockIdx.y * 128;
  const int wrow = (wid >> 1) * 64, wcol = (wid & 1) * 64;

  f32x4 acc[4][4] = {};

  const int srow = tid >> 2;              // 0..63
  const int scb  = (tid & 3) * 16;        // byte within 64B row-chunk
  const char* gA = (const char*)Bb + (size_t)(grow0 + srow) * KBYTES + scb;
  const char* gB = (const char*)Bb + (size_t)(gcol0 + srow) * KBYTES + scb;
  char* lA = (char*)As + wid * 1024;
  char* lB = (char*)Bs + wid * 1024;

  for (int kt = 0; kt < 32; ++kt) {
    __syncthreads();   // prior ds_reads done before overwrite
    const char* a0 = gA + kt * 64;
    const char* b0 = gB + kt * 64;
    __builtin_amdgcn_global_load_lds((const __attribute__((address_space(1))) void*)a0,
                                     (__attribute__((address_space(3))) void*)lA, 16, 0, 0);
    __builtin_amdgcn_global_load_lds((const __attribute__((address_space(1))) void*)(a0 + (size_t)64 * KBYTES),
                                     (__attribute__((address_space(3))) void*)(lA + 4096), 16, 0, 0);
    __builtin_amdgcn_global_load_lds((const __attribute__((address_space(1))) void*)b0,
                                     (__attribute__((address_space(3))) void*)lB, 16, 0, 0);
    __builtin_amdgcn_global_load_lds((const __attribute__((address_space(1))) void*)(b0 + (size_t)64 * KBYTES),
                                     (__attribute__((address_space(3))) void*)(lB + 4096), 16, 0, 0);
    __syncthreads();   // staging visible (compiler drains vmcnt before barrier)

    bf16x8 af[4], bfg[4];
#pragma unroll
    for (int m = 0; m < 4; ++m)
      af[m] = *(const bf16x8*)&As[(wrow + m * 16 + lo) * 32 + hi * 8];
#pragma unroll
    for (int n = 0; n < 4; ++n)
      bfg[n] = *(const bf16x8*)&Bs[(wcol + n * 16 + lo) * 32 + hi * 8];
#pragma unroll
    for (int m = 0; m < 4; ++m)
#pragma unroll
      for (int n = 0; n < 4; ++n)
        acc[m][n] = __builtin_amdgcn_mfma_f32_16x16x32_bf16(af[m], bfg[n], acc[m][n], 0, 0, 0);
  }

  // epilogue: scale -> exp2 -> mask diag -> row-reduce -> atomic
  const float C = 1.4426950408889634f / T_TEMP;   // log2(e)/T
  float invc[4], invr[4][4];
#pragma unroll
  for (int n = 0; n < 4; ++n)
    invc[n] = inv_n[gcol0 + wcol + n * 16 + lo] * C;
#pragma unroll
  for (int m = 0; m < 4; ++m)
#pragma unroll
    for (int r = 0; r < 4; ++r)
      invr[m][r] = inv_n[grow0 + wrow + m * 16 + hi * 4 + r];

  float rp[4][4] = {};
#pragma unroll
  for (int m = 0; m < 4; ++m)
#pragma unroll
    for (int n = 0; n < 4; ++n)
#pragma unroll
      for (int r = 0; r < 4; ++r) {
        const int i = grow0 + wrow + m * 16 + hi * 4 + r;
        const int j = gcol0 + wcol + n * 16 + lo;
        float e = exp2f(acc[m][n][r] * invr[m][r] * invc[n]);
        if (j == i || j == i + N_ROWS) e = 0.0f;
        rp[m][r] += e;
      }

#pragma unroll
  for (int m = 0; m < 4; ++m)
#pragma unroll
    for (int r = 0; r < 4; ++r) {
      float v = rp[m][r];
      v += __shfl_xor(v, 1, 16);
      v += __shfl_xor(v, 2, 16);
      v += __shfl_xor(v, 4, 16);
      v += __shfl_xor(v, 8, 16);
      if (lo == 0)
        atomicAdd(&rowsum[grow0 + wrow + m * 16 + hi * 4 + r], v);
    }
}

// Single block: cumsum(rowsum) -> sum(log(neg) - logpos) + js -> out[0]
__global__ __launch_bounds__(256) void final_kernel(
    const float* __restrict__ rowsum, const float* __restrict__ logpos,
    const float* __restrict__ js_acc, float* __restrict__ out) {
  __shared__ float scan[256];
  __shared__ double ds[4];
  const int tid = threadIdx.x;
  float loc[16];
  float run = 0.f;
#pragma unroll
  for (int k = 0; k < 16; ++k) { loc[k] = rowsum[tid * 16 + k]; run += loc[k]; }
  scan[tid] = run;
  __syncthreads();
  for (int d = 1; d < 256; d <<= 1) {
    float add = (tid >= d) ? scan[tid - d] : 0.0f;
    __syncthreads();
    scan[tid] += add;
    __syncthreads();
  }
  float c = scan[tid] - run;  // exclusive prefix
  double acc = 0.0;
#pragma unroll
  for (int k = 0; k < 16; ++k) {
    c += loc[k];
    acc += (double)(logf(c) - logpos[tid * 16 + k]);
  }
#pragma unroll
  for (int m = 32; m >= 1; m >>= 1) acc += __shfl_xor(acc, m, 64);
  if ((tid & 63) == 0) ds[tid >> 6] = acc;
  __syncthreads();
  if (tid == 0) {
    const double nce = ds[0] + ds[1] + ds[2] + ds[3];
    const double js = (double)js_acc[0] / (2.0 * N_ROWS);
    out[0] = (float)(nce + 1.0 * js);
  }
}

extern "C" void kernel_launch(void* const* d_in, const int* in_sizes, int n_in,
                              void* d_out, int out_size, void* d_ws, size_t ws_size,
                              hipStream_t stream) {
  const float* x = (const float*)d_in[0];
  const float* y = (const float*)d_in[1];
  float* out = (float*)d_out;

  char* ws = (char*)d_ws;
  unsigned short* Bb = (unsigned short*)ws;                 // [8192][1024] bf16, 16 MB
  float* inv_n  = (float*)(ws + (size_t)16 * 1024 * 1024);  // 8192
  float* logpos = inv_n + 8192;                             // 4096
  float* rowsum = logpos + 4096;                            // 4096
  float* js_acc = rowsum + 4096;                            // 1

  hipMemsetAsync(rowsum, 0, (4096 + 1) * sizeof(float), stream);
  prep_kernel<<<N_ROWS, 256, 0, stream>>>(x, y, Bb, inv_n, logpos, js_acc);
  gemm_fused<<<dim3(32, 64), 256, 0, stream>>>(Bb, inv_n, rowsum);
  final_kernel<<<1, 256, 0, stream>>>(rowsum, logpos, js_acc, out);
}